// Round 2
// 4352.895 us; speedup vs baseline: 1.2973x; 1.2973x over previous
//
#include <hip/hip_runtime.h>
#include <math.h>

#define H 1024
#define SEQ 256
#define VOUT 32000

__device__ __forceinline__ float sigmoidf_(float x) { return 1.f / (1.f + expf(-x)); }

// ---------------------------------------------------------------------------
// Device-coherent (cross-XCD) access helpers: relaxed agent-scope atomics.
// These bypass the non-coherent per-XCD caches WITHOUT emitting any cache
// invalidate/writeback, so read-only weights stay warm in L1/L2.
// ---------------------------------------------------------------------------
__device__ __forceinline__ float cload(const float* p) {
    return __hip_atomic_load(p, __ATOMIC_RELAXED, __HIP_MEMORY_SCOPE_AGENT);
}
__device__ __forceinline__ void cstore(float* p, float v) {
    __hip_atomic_store(p, v, __ATOMIC_RELAXED, __HIP_MEMORY_SCOPE_AGENT);
}

// ---------------------------------------------------------------------------
// Fast grid barrier: 2-level monotonic arrival tree + generation spin.
// bar layout (ints): leaf i at [i*16] (16 leaves, 64B apart), root at [320],
// gen at [384]. All zeroed by init_kernel each launch.
// Precondition: called by all 256 blocks with the same monotonically
// increasing `target` (1,2,3,...). __syncthreads() before arrival guarantees
// every wave's stores have completed (compiler emits vmcnt(0) before
// s_barrier), so coherent readers after the barrier see them.
// ---------------------------------------------------------------------------
__device__ __forceinline__ void gbar(int* bar, int target) {
    __syncthreads();
    if (threadIdx.x == 0) {
        int* leaf = bar + ((blockIdx.x & 15) << 4);
        int a = __hip_atomic_fetch_add(leaf, 1, __ATOMIC_RELAXED, __HIP_MEMORY_SCOPE_AGENT);
        if (a == 16 * target - 1) {
            int r = __hip_atomic_fetch_add(bar + 320, 1, __ATOMIC_RELAXED, __HIP_MEMORY_SCOPE_AGENT);
            if (r == 16 * target - 1) {
                __hip_atomic_store(bar + 384, target, __ATOMIC_RELAXED, __HIP_MEMORY_SCOPE_AGENT);
            }
        }
        while (__hip_atomic_load(bar + 384, __ATOMIC_RELAXED, __HIP_MEMORY_SCOPE_AGENT) < target) {
            __builtin_amdgcn_s_sleep(2);
        }
    }
    __syncthreads();
}

// ---------------------------------------------------------------------------
__global__ __launch_bounds__(256) void gather_kernel(
    const int* __restrict__ input_ids, const int* __restrict__ target_ids,
    const float* __restrict__ enc_emb, const float* __restrict__ dec_emb,
    float* __restrict__ enc_x, float* __restrict__ dec_e)
{
    int b = blockIdx.x, tid = threadIdx.x;
    if (b < SEQ) {
        int tok = input_ids[b];
        const float4* src = (const float4*)(enc_emb + (size_t)tok * H);
        float4* dst = (float4*)(enc_x + (size_t)b * H);
        dst[tid] = src[tid];
    } else {
        int t = b - SEQ;
        int tok = (t == 0) ? 1 : target_ids[t - 1];
        const float4* src = (const float4*)(dec_emb + (size_t)tok * H);
        float4* dst = (float4*)(dec_e + (size_t)t * H);
        dst[tid] = src[tid];
    }
}

// zero hbuf (2H floats) + barrier state (1024 ints) — re-run every launch
// because the harness poisons d_ws with 0xAA.
__global__ __launch_bounds__(256) void init_kernel(float* __restrict__ hbuf,
                                                   int* __restrict__ bar)
{
    int i = blockIdx.x * 256 + threadIdx.x;
    if (i < 2 * H) hbuf[i] = 0.f;
    if (i < 1024) bar[i] = 0;
}

// ---------------------------------------------------------------------------
// Generic NT GEMM: C[m,n] = sum_k A[m*lda+offa+k] * B[n*ldb+k] (+ bias[n])
// ---------------------------------------------------------------------------
__global__ __launch_bounds__(256) void gemm_nt_kernel(
    const float* __restrict__ A, const float* __restrict__ B,
    const float* __restrict__ bias, float* __restrict__ C,
    int Kdim, int lda, int offa, int ldb, int ldc)
{
    __shared__ float As[16][68];
    __shared__ float Bs[16][68];
    const int tid = threadIdx.x;
    const int m0 = blockIdx.y * 64;
    const int n0 = blockIdx.x * 64;
    const int tr = (tid >> 4) << 2;
    const int tc = (tid & 15) << 2;
    const int lrow = tid >> 2;
    const int lk = (tid & 3) << 2;
    const float* Ab = A + (size_t)m0 * lda + offa;
    const float* Bb = B + (size_t)n0 * ldb;
    float acc[4][4] = {{0.f,0.f,0.f,0.f},{0.f,0.f,0.f,0.f},{0.f,0.f,0.f,0.f},{0.f,0.f,0.f,0.f}};

    for (int k0 = 0; k0 < Kdim; k0 += 16) {
        float4 av = *(const float4*)(Ab + (size_t)lrow * lda + (k0 + lk));
        float4 bv = *(const float4*)(Bb + (size_t)lrow * ldb + (k0 + lk));
        As[lk + 0][lrow] = av.x; As[lk + 1][lrow] = av.y;
        As[lk + 2][lrow] = av.z; As[lk + 3][lrow] = av.w;
        Bs[lk + 0][lrow] = bv.x; Bs[lk + 1][lrow] = bv.y;
        Bs[lk + 2][lrow] = bv.z; Bs[lk + 3][lrow] = bv.w;
        __syncthreads();
#pragma unroll
        for (int k = 0; k < 16; ++k) {
            float4 a = *(const float4*)(&As[k][tr]);
            float4 b = *(const float4*)(&Bs[k][tc]);
            acc[0][0] = fmaf(a.x, b.x, acc[0][0]);
            acc[0][1] = fmaf(a.x, b.y, acc[0][1]);
            acc[0][2] = fmaf(a.x, b.z, acc[0][2]);
            acc[0][3] = fmaf(a.x, b.w, acc[0][3]);
            acc[1][0] = fmaf(a.y, b.x, acc[1][0]);
            acc[1][1] = fmaf(a.y, b.y, acc[1][1]);
            acc[1][2] = fmaf(a.y, b.z, acc[1][2]);
            acc[1][3] = fmaf(a.y, b.w, acc[1][3]);
            acc[2][0] = fmaf(a.z, b.x, acc[2][0]);
            acc[2][1] = fmaf(a.z, b.y, acc[2][1]);
            acc[2][2] = fmaf(a.z, b.z, acc[2][2]);
            acc[2][3] = fmaf(a.z, b.w, acc[2][3]);
            acc[3][0] = fmaf(a.w, b.x, acc[3][0]);
            acc[3][1] = fmaf(a.w, b.y, acc[3][1]);
            acc[3][2] = fmaf(a.w, b.z, acc[3][2]);
            acc[3][3] = fmaf(a.w, b.w, acc[3][3]);
        }
        __syncthreads();
    }
#pragma unroll
    for (int i = 0; i < 4; ++i) {
#pragma unroll
        for (int j = 0; j < 4; ++j) {
            float v = acc[i][j];
            if (bias) v += bias[n0 + tc + j];
            C[(size_t)(m0 + tr + i) * ldc + (n0 + tc + j)] = v;
        }
    }
}

// ---------------------------------------------------------------------------
// Encoder recurrence: 256 blocks x 256 threads, wave w of block b owns unit
// u = b*4+w. One custom barrier per step. All 3 Wh rows for unit u are held
// in registers (48 VGPR/lane) — loop-invariant, so the per-step dependent
// section is just: barrier -> coherent h broadcast -> LDS reads + reg FMAs.
// ---------------------------------------------------------------------------
__global__ __launch_bounds__(256, 1) void enc_rnn_kernel(
    const float* __restrict__ Wh, const float* __restrict__ bh,
    const float* __restrict__ gi_all,
    float* __restrict__ hbuf, float* __restrict__ encH, int* __restrict__ bar)
{
    __shared__ float h_s[H];
    const int tid = threadIdx.x;
    const int wave = tid >> 6, lane = tid & 63;
    const int u = blockIdx.x * 4 + wave;

    // loop-invariant weight rows -> registers (indices are compile-time after
    // full unroll, so these stay in VGPRs, never scratch)
    float rWr[16], rWz[16], rWn[16];
    {
        const float* wr = Wh + (size_t)u * H;
        const float* wz = Wh + (size_t)(u + H) * H;
        const float* wn = Wh + (size_t)(u + 2 * H) * H;
#pragma unroll
        for (int i = 0; i < 16; ++i) {
            int k = lane + (i << 6);
            rWr[i] = wr[k]; rWz[i] = wz[k]; rWn[i] = wn[k];
        }
    }
    const float bhr = bh[u], bhz = bh[H + u], bhn = bh[2 * H + u];

    for (int t = 0; t < SEQ; ++t) {
        const float* h = hbuf + (t & 1) * H;
        float* hnext = hbuf + ((t + 1) & 1) * H;
        // prefetch this step's input-gate values (L2-resident, independent of h)
        const float g0 = gi_all[t * 3 * H + u];
        const float g1 = gi_all[t * 3 * H + H + u];
        const float g2 = gi_all[t * 3 * H + 2 * H + u];

        for (int i = tid; i < H; i += 256) h_s[i] = cload(h + i);
        __syncthreads();

        float dr = 0.f, dz = 0.f, dn = 0.f;
#pragma unroll
        for (int i = 0; i < 16; ++i) {
            float hv = h_s[lane + (i << 6)];
            dr = fmaf(rWr[i], hv, dr);
            dz = fmaf(rWz[i], hv, dz);
            dn = fmaf(rWn[i], hv, dn);
        }
#pragma unroll
        for (int off = 32; off > 0; off >>= 1) {
            dr += __shfl_down(dr, off);
            dz += __shfl_down(dz, off);
            dn += __shfl_down(dn, off);
        }
        if (lane == 0) {
            float r = sigmoidf_(g0 + dr + bhr);
            float z = sigmoidf_(g1 + dz + bhz);
            float n = tanhf(g2 + r * (dn + bhn));
            float h2 = (1.f - z) * n + z * h_s[u];
            cstore(hnext + u, h2);
            encH[(size_t)t * H + u] = h2;
        }
        gbar(bar, t + 1);
    }
}

// ---------------------------------------------------------------------------
// Decoder recurrence: 3 custom barriers per step. All loop-invariant operands
// (6 GRU weight rows, attn row, M row, biases) live in registers (~110 VGPR),
// so each stage's dependent section is one coherent-load round trip + reg FMAs.
// ---------------------------------------------------------------------------
__global__ __launch_bounds__(256, 1) void dec_rnn_kernel(
    const float* __restrict__ attn_W, const float* __restrict__ attn_e,
    const float* __restrict__ M, const float* __restrict__ comb_pre,
    const float* __restrict__ Wi, const float* __restrict__ Wh,
    const float* __restrict__ bi, const float* __restrict__ bh,
    float* __restrict__ hbuf, float* __restrict__ s_g,
    float* __restrict__ c_g, float* __restrict__ hs_dec, int* __restrict__ bar)
{
    __shared__ float h_s[H];
    __shared__ float c_s[H];
    __shared__ float a_s[SEQ];
    __shared__ float red4[4];
    const int b = blockIdx.x, tid = threadIdx.x;
    const int wave = tid >> 6, lane = tid & 63;
    const int u = b * 4 + wave;

    // ---- loop-invariant operands -> registers ----
    float rWir[16], rWiz[16], rWin[16], rWhr[16], rWhz[16], rWhn[16];
    {
        const float* wir = Wi + (size_t)u * H;
        const float* wiz = Wi + (size_t)(u + H) * H;
        const float* win = Wi + (size_t)(u + 2 * H) * H;
        const float* whr = Wh + (size_t)u * H;
        const float* whz = Wh + (size_t)(u + H) * H;
        const float* whn = Wh + (size_t)(u + 2 * H) * H;
#pragma unroll
        for (int i = 0; i < 16; ++i) {
            int k = lane + (i << 6);
            rWir[i] = wir[k]; rWiz[i] = wiz[k]; rWin[i] = win[k];
            rWhr[i] = whr[k]; rWhz[i] = whz[k]; rWhn[i] = whn[k];
        }
    }
    float rA[4];
    {
        const float* arow = attn_W + (size_t)b * (2 * H) + H;
#pragma unroll
        for (int j = 0; j < 4; ++j) rA[j] = arow[tid + (j << 8)];
    }
    float rM[4];
    {
        const float* Mrow = M + (size_t)u * SEQ;
#pragma unroll
        for (int j = 0; j < 4; ++j) rM[j] = Mrow[lane + (j << 6)];
    }
    const float bir = bi[u], biz = bi[H + u], bin_ = bi[2 * H + u];
    const float bhr = bh[u], bhz = bh[H + u], bhn = bh[2 * H + u];

    for (int t = 0; t < SEQ; ++t) {
        const float* h = hbuf + (t & 1) * H;
        float* hnext = hbuf + ((t + 1) & 1) * H;
        // prefetch per-step constants (independent of recurrent state)
        const float aev  = attn_e[t * SEQ + b];
        const float cpre = comb_pre[t * H + u];

        // coherent h broadcast: registers feed stage 1 directly, LDS copy
        // feeds stage 3 (different access layout)
        float hr0 = cload(h + tid);
        float hr1 = cload(h + tid + 256);
        float hr2 = cload(h + tid + 512);
        float hr3 = cload(h + tid + 768);
        h_s[tid]       = hr0;
        h_s[tid + 256] = hr1;
        h_s[tid + 512] = hr2;
        h_s[tid + 768] = hr3;

        // ---- stage 1: score[b] = attn_e[t,b] + attn_W[b,H:] @ h ----
        float p = fmaf(rA[0], hr0, 0.f);
        p = fmaf(rA[1], hr1, p);
        p = fmaf(rA[2], hr2, p);
        p = fmaf(rA[3], hr3, p);
#pragma unroll
        for (int off = 32; off > 0; off >>= 1) p += __shfl_down(p, off);
        if (lane == 0) red4[wave] = p;
        __syncthreads();                 // red4 ready; h_s visible for stage 3
        if (tid == 0)
            cstore(s_g + b, red4[0] + red4[1] + red4[2] + red4[3] + aev);
        gbar(bar, 3 * t + 1);

        // ---- stage 2: softmax (block-redundant) + c[u] ----
        float sv = cload(s_g + tid);
        float m = sv;
#pragma unroll
        for (int off = 32; off > 0; off >>= 1) m = fmaxf(m, __shfl_down(m, off));
        if (lane == 0) red4[wave] = m;
        __syncthreads();
        float mx = fmaxf(fmaxf(red4[0], red4[1]), fmaxf(red4[2], red4[3]));
        float ev = expf(sv - mx);
        a_s[tid] = ev;
        float ssum = ev;
#pragma unroll
        for (int off = 32; off > 0; off >>= 1) ssum += __shfl_down(ssum, off);
        __syncthreads();                 // readers of red4 (mx) done; a_s visible
        if (lane == 0) red4[wave] = ssum;
        __syncthreads();
        float inv = 1.f / (red4[0] + red4[1] + red4[2] + red4[3]);
        float pc = fmaf(a_s[lane], rM[0], 0.f);
        pc = fmaf(a_s[lane + 64],  rM[1], pc);
        pc = fmaf(a_s[lane + 128], rM[2], pc);
        pc = fmaf(a_s[lane + 192], rM[3], pc);
#pragma unroll
        for (int off = 32; off > 0; off >>= 1) pc += __shfl_down(pc, off);
        if (lane == 0)
            cstore(c_g + u, fmaxf(0.f, cpre + pc * inv));
        gbar(bar, 3 * t + 2);

        // ---- stage 3: GRU cell (weights already in registers) ----
        c_s[tid]       = cload(c_g + tid);
        c_s[tid + 256] = cload(c_g + tid + 256);
        c_s[tid + 512] = cload(c_g + tid + 512);
        c_s[tid + 768] = cload(c_g + tid + 768);
        __syncthreads();
        float dir = 0.f, diz = 0.f, din = 0.f, dhr = 0.f, dhz = 0.f, dhn = 0.f;
#pragma unroll
        for (int i = 0; i < 16; ++i) {
            int k = lane + (i << 6);
            float cv = c_s[k], hv = h_s[k];
            dir = fmaf(rWir[i], cv, dir);
            diz = fmaf(rWiz[i], cv, diz);
            din = fmaf(rWin[i], cv, din);
            dhr = fmaf(rWhr[i], hv, dhr);
            dhz = fmaf(rWhz[i], hv, dhz);
            dhn = fmaf(rWhn[i], hv, dhn);
        }
#pragma unroll
        for (int off = 32; off > 0; off >>= 1) {
            dir += __shfl_down(dir, off); diz += __shfl_down(diz, off);
            din += __shfl_down(din, off); dhr += __shfl_down(dhr, off);
            dhz += __shfl_down(dhz, off); dhn += __shfl_down(dhn, off);
        }
        if (lane == 0) {
            float r = sigmoidf_(dir + bir + dhr + bhr);
            float z = sigmoidf_(diz + biz + dhz + bhz);
            float n = tanhf(din + bin_ + r * (dhn + bhn));
            float h2 = (1.f - z) * n + z * h_s[u];
            cstore(hnext + u, h2);
            hs_dec[(size_t)t * H + u] = h2;
        }
        gbar(bar, 3 * t + 3);
    }
}

// ---------------------------------------------------------------------------
__global__ __launch_bounds__(256) void nll_kernel(
    const float* __restrict__ logits, const int* __restrict__ target_ids,
    float* __restrict__ nll)
{
    const int t = blockIdx.x, tid = threadIdx.x;
    __shared__ float red[256];
    const float* row = logits + (size_t)t * VOUT;
    float mx = -1e30f;
    for (int i = tid; i < VOUT; i += 256) mx = fmaxf(mx, row[i]);
    red[tid] = mx;
    __syncthreads();
    for (int off = 128; off > 0; off >>= 1) {
        if (tid < off) red[tid] = fmaxf(red[tid], red[tid + off]);
        __syncthreads();
    }
    mx = red[0];
    __syncthreads();
    float s = 0.f;
    for (int i = tid; i < VOUT; i += 256) s += expf(row[i] - mx);
    red[tid] = s;
    __syncthreads();
    for (int off = 128; off > 0; off >>= 1) {
        if (tid < off) red[tid] += red[tid + off];
        __syncthreads();
    }
    if (tid == 0) {
        float lse = mx + logf(red[0]);
        nll[t] = lse - row[target_ids[t]];
    }
}

__global__ __launch_bounds__(256) void sum_kernel(
    const float* __restrict__ nll, float* __restrict__ out)
{
    __shared__ float red[256];
    int tid = threadIdx.x;
    red[tid] = nll[tid];
    __syncthreads();
    for (int off = 128; off > 0; off >>= 1) {
        if (tid < off) red[tid] += red[tid + off];
        __syncthreads();
    }
    if (tid == 0) out[0] = red[0];
}

// ---------------------------------------------------------------------------
extern "C" void kernel_launch(void* const* d_in, const int* in_sizes, int n_in,
                              void* d_out, int out_size, void* d_ws, size_t ws_size,
                              hipStream_t stream)
{
    const int*   input_ids  = (const int*)d_in[0];
    const int*   target_ids = (const int*)d_in[1];
    const float* enc_emb = (const float*)d_in[2];
    const float* enc_Wi  = (const float*)d_in[3];
    const float* enc_Wh  = (const float*)d_in[4];
    const float* enc_bi  = (const float*)d_in[5];
    const float* enc_bh  = (const float*)d_in[6];
    const float* dec_emb = (const float*)d_in[7];
    const float* dec_Wi  = (const float*)d_in[8];
    const float* dec_Wh  = (const float*)d_in[9];
    const float* dec_bi  = (const float*)d_in[10];
    const float* dec_bh  = (const float*)d_in[11];
    const float* attn_W  = (const float*)d_in[12];
    const float* attn_b  = (const float*)d_in[13];
    const float* comb_W  = (const float*)d_in[14];
    const float* comb_b  = (const float*)d_in[15];
    const float* out_W   = (const float*)d_in[16];
    const float* out_b   = (const float*)d_in[17];
    float* out = (float*)d_out;

    float* ws = (float*)d_ws;
    float* enc_x    = ws; ws += SEQ * H;
    float* dec_e    = ws; ws += SEQ * H;
    float* enc_gi   = ws; ws += SEQ * 3 * H;
    float* attn_e   = ws; ws += SEQ * SEQ;
    float* comb_pre = ws; ws += SEQ * H;
    float* Mmat     = ws; ws += H * SEQ;
    float* encH     = ws; ws += SEQ * H;
    float* hs_dec   = ws; ws += SEQ * H;
    float* hbuf     = ws; ws += 2 * H;
    float* s_g      = ws; ws += SEQ;
    float* c_g      = ws; ws += H;
    float* nll      = ws; ws += SEQ;
    int*   bar_all  = (int*)ws; ws += 1024;       // enc bar at +0, dec bar at +512
    ws += (256 - ((ws - (float*)d_ws) & 255)) & 255;
    float* logits   = ws; ws += (size_t)SEQ * VOUT;

    int* bar_enc = bar_all;
    int* bar_dec = bar_all + 512;

    // phase 0: gathers + zero h/barriers
    hipLaunchKernelGGL(gather_kernel, dim3(512), dim3(256), 0, stream,
                       input_ids, target_ids, enc_emb, dec_emb, enc_x, dec_e);
    hipLaunchKernelGGL(init_kernel, dim3(16), dim3(256), 0, stream, hbuf, bar_all);

    // phase 1: batched pre-GEMMs
    hipLaunchKernelGGL(gemm_nt_kernel, dim3(3 * H / 64, SEQ / 64), dim3(256), 0, stream,
                       enc_x, enc_Wi, enc_bi, enc_gi, H, H, 0, H, 3 * H);
    hipLaunchKernelGGL(gemm_nt_kernel, dim3(SEQ / 64, SEQ / 64), dim3(256), 0, stream,
                       dec_e, attn_W, attn_b, attn_e, H, H, 0, 2 * H, SEQ);
    hipLaunchKernelGGL(gemm_nt_kernel, dim3(H / 64, SEQ / 64), dim3(256), 0, stream,
                       dec_e, comb_W, comb_b, comb_pre, H, H, 0, 2 * H, H);

    // phase 2: encoder recurrence (cooperative launch for residency guarantee)
    {
        void* args[] = {(void*)&enc_Wh, (void*)&enc_bh, (void*)&enc_gi,
                        (void*)&hbuf, (void*)&encH, (void*)&bar_enc};
        hipLaunchCooperativeKernel((void*)enc_rnn_kernel, dim3(256), dim3(256),
                                   args, 0, stream);
    }

    // phase 2.5: M = comb_W[:,H:] @ encH^T
    hipLaunchKernelGGL(gemm_nt_kernel, dim3(SEQ / 64, H / 64), dim3(256), 0, stream,
                       comb_W, encH, (const float*)nullptr, Mmat, H, 2 * H, H, H, SEQ);

    // phase 3: decoder recurrence
    {
        void* args[] = {(void*)&attn_W, (void*)&attn_e, (void*)&Mmat, (void*)&comb_pre,
                        (void*)&dec_Wi, (void*)&dec_Wh, (void*)&dec_bi, (void*)&dec_bh,
                        (void*)&hbuf, (void*)&s_g, (void*)&c_g, (void*)&hs_dec,
                        (void*)&bar_dec};
        hipLaunchCooperativeKernel((void*)dec_rnn_kernel, dim3(256), dim3(256),
                                   args, 0, stream);
    }

    // phase 4: logits = hs_dec @ out_W^T + out_b
    hipLaunchKernelGGL(gemm_nt_kernel, dim3(VOUT / 64, SEQ / 64), dim3(256), 0, stream,
                       hs_dec, out_W, out_b, logits, H, H, 0, H, VOUT);

    // phase 5: NLL + total
    hipLaunchKernelGGL(nll_kernel, dim3(SEQ), dim3(256), 0, stream,
                       logits, target_ids, nll);
    hipLaunchKernelGGL(sum_kernel, dim3(1), dim3(256), 0, stream, nll, out);
}